// Round 5
// baseline (867.830 us; speedup 1.0000x reference)
//
#include <hip/hip_runtime.h>
#include <cstdint>

#define NU 100000
#define NI 100000
#define NN 200000
#define NE 3200000
#define TXT 768
#define DD 32
#define NRANGE 8
#define ROWS_PER_RANGE (NN / NRANGE)   // 25000
#define NBJ 313        // blocks per range for ranged kernels

typedef _Float16 f16x8 __attribute__((ext_vector_type(8)));
typedef _Float16 f16x4 __attribute__((ext_vector_type(4)));
typedef float    f32x4 __attribute__((ext_vector_type(4)));

__device__ __forceinline__ float lrelu(float x) { return x >= 0.f ? x : 0.01f * x; }

// ---------------------------------------------------------------------------
// Copy pretrained 16-dim embeddings into ego16[:,0:16] (f16) and out[:,0:16]
// ---------------------------------------------------------------------------
__global__ void copy_emb_kernel(const float* __restrict__ uemb,
                                const float* __restrict__ iemb,
                                _Float16* __restrict__ ego16,
                                float* __restrict__ outp)
{
    int idx = blockIdx.x * blockDim.x + threadIdx.x;
    if (idx >= NN * 4) return;
    int n = idx >> 2, q = idx & 3;
    float4 v;
    if (n < NU) v = ((const float4*)uemb)[(size_t)n * 4 + q];
    else        v = ((const float4*)iemb)[(size_t)(n - NU) * 4 + q];
    f16x4 h;
    h[0] = (_Float16)v.x; h[1] = (_Float16)v.y;
    h[2] = (_Float16)v.z; h[3] = (_Float16)v.w;
    *(f16x4*)(ego16 + (size_t)n * 32 + q * 4) = h;
    ((float4*)outp)[(size_t)n * 32 + q] = v;
}

// ---------------------------------------------------------------------------
// MFMA MLP: created = relu(X @ W1) @ W2 ; writes ego16[:,16:32], out[:,16:32].
// One wave per 16-row tile; W1 f16 slot-linear in LDS; both matmuls on MFMA.
// ---------------------------------------------------------------------------
__global__ __launch_bounds__(512) void mlp_mfma_kernel(
    const float* __restrict__ X,    // 100000 x 768
    const float* __restrict__ W1,   // 768 x 32
    const float* __restrict__ W2,   // 32 x 16
    _Float16* __restrict__ ego16,
    float* __restrict__ outp,
    int node_base)
{
    __shared__ _Float16 W1s[24576];      // 48 KB: [kb(24)][half(2)][lane(64)][j(8)]
    __shared__ _Float16 hbuf[8][640];    // per-wave 16 x 40 (h, row-major, padded)

    const int tid  = threadIdx.x;
    const int lane = tid & 63;
    const int wv   = tid >> 6;

    for (int i = tid; i < 24576; i += 512) {
        int j   = i & 7;
        int ln  = (i >> 3) & 63;
        int kbH = i >> 9;
        int kb  = kbH >> 1, H = kbH & 1;
        int k   = kb * 32 + (ln >> 4) * 8 + j;
        int c   = H * 16 + (ln & 15);
        W1s[i] = (_Float16)W1[k * 32 + c];
    }

    f16x8 bw2;
    #pragma unroll
    for (int j = 0; j < 8; ++j)
        bw2[j] = (_Float16)W2[((lane >> 4) * 8 + j) * 16 + (lane & 15)];

    __syncthreads();

    _Float16* hb = &hbuf[wv][0];
    const int gw = blockIdx.x * 8 + wv;                 // 0..4095 (512 blocks)
    const int t0 = (int)(((long)gw * 6250) >> 12);      // balanced tile ranges
    const int t1 = (int)(((long)(gw + 1) * 6250) >> 12);

    for (int tile = t0; tile < t1; ++tile) {
        const float* xp = X + (size_t)(tile * 16 + (lane & 15)) * TXT + (lane >> 4) * 8;
        f32x4 c0 = {0.f, 0.f, 0.f, 0.f};
        f32x4 c1 = {0.f, 0.f, 0.f, 0.f};

        #pragma unroll 4
        for (int kb = 0; kb < 24; ++kb) {
            float4 xa = *(const float4*)(xp + kb * 32);
            float4 xb = *(const float4*)(xp + kb * 32 + 4);
            f16x8 a;
            a[0] = (_Float16)xa.x; a[1] = (_Float16)xa.y;
            a[2] = (_Float16)xa.z; a[3] = (_Float16)xa.w;
            a[4] = (_Float16)xb.x; a[5] = (_Float16)xb.y;
            a[6] = (_Float16)xb.z; a[7] = (_Float16)xb.w;
            f16x8 b0 = *(const f16x8*)&W1s[(kb * 2 + 0) * 512 + lane * 8];
            f16x8 b1 = *(const f16x8*)&W1s[(kb * 2 + 1) * 512 + lane * 8];
            c0 = __builtin_amdgcn_mfma_f32_16x16x32_f16(a, b0, c0, 0, 0, 0);
            c1 = __builtin_amdgcn_mfma_f32_16x16x32_f16(a, b1, c1, 0, 0, 0);
        }

        #pragma unroll
        for (int j = 0; j < 4; ++j) {
            int r = (lane >> 4) * 4 + j;
            hb[r * 40 + (lane & 15)]      = (_Float16)fmaxf(c0[j], 0.f);
            hb[r * 40 + (lane & 15) + 16] = (_Float16)fmaxf(c1[j], 0.f);
        }
        const _Float16* ap = &hb[(lane & 15) * 40 + (lane >> 4) * 8];
        f16x4 lo = *(const f16x4*)ap;
        f16x4 hi = *(const f16x4*)(ap + 4);
        f16x8 a2;
        a2[0] = lo[0]; a2[1] = lo[1]; a2[2] = lo[2]; a2[3] = lo[3];
        a2[4] = hi[0]; a2[5] = hi[1]; a2[6] = hi[2]; a2[7] = hi[3];

        f32x4 c2 = {0.f, 0.f, 0.f, 0.f};
        c2 = __builtin_amdgcn_mfma_f32_16x16x32_f16(a2, bw2, c2, 0, 0, 0);

        const int rbase = node_base + tile * 16 + (lane >> 4) * 4;
        const int j2 = lane & 15;
        #pragma unroll
        for (int j = 0; j < 4; ++j) {
            float v = c2[j];
            ego16[(size_t)(rbase + j) * 32  + 16 + j2] = (_Float16)v;
            outp [(size_t)(rbase + j) * 128 + 16 + j2] = v;
        }
    }
}

// ---------------------------------------------------------------------------
// XCD-range-partitioned CSR build (block b&7 owns a row range -> L2-local)
// ---------------------------------------------------------------------------
__global__ __launch_bounds__(256) void count_ranged_kernel(const int* __restrict__ erow,
                                                           int* __restrict__ cnt)
{
    const int rlo = (blockIdx.x & 7) * ROWS_PER_RANGE;
    const int rhi = rlo + ROWS_PER_RANGE;
    const int bj  = blockIdx.x >> 3;
    const int4* e4 = (const int4*)erow;
    for (int c = bj * 256 + threadIdx.x; c < NE / 4; c += NBJ * 256) {
        int4 v = e4[c];
        if (v.x >= rlo && v.x < rhi) atomicAdd(&cnt[v.x], 1);
        if (v.y >= rlo && v.y < rhi) atomicAdd(&cnt[v.y], 1);
        if (v.z >= rlo && v.z < rhi) atomicAdd(&cnt[v.z], 1);
        if (v.w >= rlo && v.w < rhi) atomicAdd(&cnt[v.w], 1);
    }
}

__global__ __launch_bounds__(256) void scan_blk_kernel(const int* __restrict__ cnt,
                                                       int* __restrict__ rp,
                                                       int* __restrict__ bsum)
{
    __shared__ int ts[256];
    const int tid = threadIdx.x;
    const int base = blockIdx.x * 1024 + tid * 4;
    int v0 = (base + 0 < NN) ? cnt[base + 0] : 0;
    int v1 = (base + 1 < NN) ? cnt[base + 1] : 0;
    int v2 = (base + 2 < NN) ? cnt[base + 2] : 0;
    int v3 = (base + 3 < NN) ? cnt[base + 3] : 0;
    int s = v0 + v1 + v2 + v3;
    ts[tid] = s;
    __syncthreads();
    for (int off = 1; off < 256; off <<= 1) {
        int t = (tid >= off) ? ts[tid - off] : 0;
        __syncthreads();
        ts[tid] += t;
        __syncthreads();
    }
    int excl = ts[tid] - s;
    if (base + 0 < NN) rp[base + 0] = excl;
    if (base + 1 < NN) rp[base + 1] = excl + v0;
    if (base + 2 < NN) rp[base + 2] = excl + v0 + v1;
    if (base + 3 < NN) rp[base + 3] = excl + v0 + v1 + v2;
    if (tid == 255) bsum[blockIdx.x] = ts[255];
}

__global__ __launch_bounds__(256) void scan_bsum_kernel(int* __restrict__ bsum, int nblk)
{
    __shared__ int ts[256];
    const int tid = threadIdx.x;
    int v = (tid < nblk) ? bsum[tid] : 0;
    ts[tid] = v;
    __syncthreads();
    for (int off = 1; off < 256; off <<= 1) {
        int t = (tid >= off) ? ts[tid - off] : 0;
        __syncthreads();
        ts[tid] += t;
        __syncthreads();
    }
    if (tid < nblk) bsum[tid] = ts[tid] - v;
}

__global__ __launch_bounds__(256) void add_off_kernel(int* __restrict__ rp,
                                                      const int* __restrict__ bsum,
                                                      int* __restrict__ cur)
{
    int i = blockIdx.x * 256 + threadIdx.x;
    if (i < NN) {
        int v = rp[i] + bsum[i >> 10];
        rp[i] = v;
        cur[i] = v;
    }
    if (i == 0) rp[NN] = NE;
}

__global__ __launch_bounds__(256) void fill_ranged_kernel(const int* __restrict__ erow,
                                                          const int* __restrict__ ecol,
                                                          const float* __restrict__ eval,
                                                          int* __restrict__ cur,
                                                          uint2* __restrict__ recs)
{
    const int rlo = (blockIdx.x & 7) * ROWS_PER_RANGE;
    const int rhi = rlo + ROWS_PER_RANGE;
    const int bj  = blockIdx.x >> 3;
    const int4* e4 = (const int4*)erow;
    for (int c = bj * 256 + threadIdx.x; c < NE / 4; c += NBJ * 256) {
        int4 v = e4[c];
        int base = c * 4;
        if (v.x >= rlo && v.x < rhi) {
            int pos = atomicAdd(&cur[v.x], 1);
            recs[pos] = make_uint2((unsigned)ecol[base+0], __float_as_uint(eval[base+0]));
        }
        if (v.y >= rlo && v.y < rhi) {
            int pos = atomicAdd(&cur[v.y], 1);
            recs[pos] = make_uint2((unsigned)ecol[base+1], __float_as_uint(eval[base+1]));
        }
        if (v.z >= rlo && v.z < rhi) {
            int pos = atomicAdd(&cur[v.z], 1);
            recs[pos] = make_uint2((unsigned)ecol[base+2], __float_as_uint(eval[base+2]));
        }
        if (v.w >= rlo && v.w < rhi) {
            int pos = atomicAdd(&cur[v.w], 1);
            recs[pos] = make_uint2((unsigned)ecol[base+3], __float_as_uint(eval[base+3]));
        }
    }
}

// ---------------------------------------------------------------------------
// Fused pull + update. 4 nodes/block. Gather phase: wave per node, 8 edge
// slots x 8 dim-lanes, f16 ego rows (64 B = one line per gather). Epilogue:
// 64 lanes per node (0-31 gc term, 32-63 bi term), W coalesced from global.
// Reads ego16In, writes ego16Out (double buffered) + outp.
// ---------------------------------------------------------------------------
__global__ __launch_bounds__(256) void pull_update_kernel(
    const int* __restrict__ rp, const uint2* __restrict__ recs,
    const _Float16* __restrict__ ego16In, _Float16* __restrict__ ego16Out,
    float* __restrict__ outp,
    const float* __restrict__ gcW, const float* __restrict__ gcb,
    const float* __restrict__ biW, const float* __restrict__ bib, int l)
{
    __shared__ float sS[4][32];
    __shared__ float eS[4][32];

    const int tid  = threadIdx.x;
    const int lane = tid & 63;
    const int wv   = tid >> 6;
    const int node = blockIdx.x * 4 + wv;
    const int slot = lane >> 3;   // edge slot 0..7
    const int q    = lane & 7;    // dim quad: dims q*4..q*4+3
    const int start = rp[node], end = rp[node + 1];

    float4 acc = make_float4(0.f, 0.f, 0.f, 0.f);
    for (int e = start + slot; e < end; e += 8) {
        uint2 rec = recs[e];
        float a = __uint_as_float(rec.y);
        f16x4 v = *(const f16x4*)(ego16In + (size_t)rec.x * 32 + q * 4);
        acc.x += a * (float)v[0];
        acc.y += a * (float)v[1];
        acc.z += a * (float)v[2];
        acc.w += a * (float)v[3];
    }
    #pragma unroll
    for (int m = 8; m <= 32; m <<= 1) {
        acc.x += __shfl_xor(acc.x, m, 64);
        acc.y += __shfl_xor(acc.y, m, 64);
        acc.z += __shfl_xor(acc.z, m, 64);
        acc.w += __shfl_xor(acc.w, m, 64);
    }
    if (slot == 0) {
        ((float4*)sS[wv])[q] = acc;
        f16x4 ev = *(const f16x4*)(ego16In + (size_t)node * 32 + q * 4);
        float4 ep = make_float4(acc.x * (float)ev[0], acc.y * (float)ev[1],
                                acc.z * (float)ev[2], acc.w * (float)ev[3]);
        ((float4*)eS[wv])[q] = ep;
    }
    __syncthreads();

    // epilogue: lanes 0-31 -> A (gc), lanes 32-63 -> B (bi)
    const int j   = lane & 31;
    const bool isB = lane >= 32;
    const float* Wrow = (isB ? biW : gcW) + (size_t)l * 1024 + j;
    const float* src  = isB ? eS[wv] : sS[wv];
    float a = (isB ? bib : gcb)[l * 32 + j];
    #pragma unroll 8
    for (int k = 0; k < 32; ++k) a += src[k] * Wrow[k * 32];
    float my = lrelu(a);
    float other = __shfl_xor(my, 32, 64);
    float v = my + other;

    float ss = v * v;
    #pragma unroll
    for (int m = 1; m <= 16; m <<= 1) ss += __shfl_xor(ss, m, 64);
    float inv = 1.0f / fmaxf(sqrtf(ss), 1e-12f);

    if (!isB) {
        ego16Out[(size_t)node * 32 + j] = (_Float16)v;
        outp[(size_t)node * 128 + (size_t)(l + 1) * 32 + j] = v * inv;
    }
}

// ---------------------------------------------------------------------------
extern "C" void kernel_launch(void* const* d_in, const int* in_sizes, int n_in,
                              void* d_out, int out_size, void* d_ws, size_t ws_size,
                              hipStream_t stream)
{
    const int*   erow = (const int*)d_in[0];
    const int*   ecol = (const int*)d_in[1];
    const float* evalp = (const float*)d_in[2];
    const float* une  = (const float*)d_in[3];
    const float* se   = (const float*)d_in[4];
    const float* uemb = (const float*)d_in[5];
    const float* iemb = (const float*)d_in[6];
    const float* ueW1 = (const float*)d_in[7];
    const float* ueW2 = (const float*)d_in[8];
    const float* ieW1 = (const float*)d_in[9];
    const float* ieW2 = (const float*)d_in[10];
    const float* gcW  = (const float*)d_in[11];
    const float* gcb  = (const float*)d_in[12];
    const float* biW  = (const float*)d_in[13];
    const float* bib  = (const float*)d_in[14];
    float* outp = (float*)d_out;

    _Float16* egoA16 = (_Float16*)d_ws;                 // NN*32 f16 = 12.8 MB
    _Float16* egoB16 = egoA16 + (size_t)NN * 32;        // 12.8 MB
    uint2* recs = (uint2*)(egoB16 + (size_t)NN * 32);   // NE uint2 = 25.6 MB
    int*   cnt  = (int*)(recs + (size_t)NE);            // NN
    int*   rp   = cnt + NN;                             // NN+1
    int*   cur  = rp + NN + 1;                          // NN
    int*   bsum = cur + NN;                             // 256

    const size_t need = (size_t)((char*)(bsum + 256) - (char*)d_ws);
    if (ws_size < need) return;   // ws is ~GB in this harness; guard only

    copy_emb_kernel<<<(NN * 4 + 255) / 256, 256, 0, stream>>>(uemb, iemb, egoA16, outp);
    mlp_mfma_kernel<<<512, 512, 0, stream>>>(une, ueW1, ueW2, egoA16, outp, 0);
    mlp_mfma_kernel<<<512, 512, 0, stream>>>(se, ieW1, ieW2, egoA16, outp, NU);

    const int NBLK = (NN + 1023) / 1024;  // 196
    hipMemsetAsync(cnt, 0, (size_t)NN * sizeof(int), stream);
    count_ranged_kernel<<<NRANGE * NBJ, 256, 0, stream>>>(erow, cnt);
    scan_blk_kernel<<<NBLK, 256, 0, stream>>>(cnt, rp, bsum);
    scan_bsum_kernel<<<1, 256, 0, stream>>>(bsum, NBLK);
    add_off_kernel<<<(NN + 255) / 256, 256, 0, stream>>>(rp, bsum, cur);
    fill_ranged_kernel<<<NRANGE * NBJ, 256, 0, stream>>>(erow, ecol, evalp, cur, recs);

    const _Float16* egoIn = egoA16;
    _Float16* egoOut = egoB16;
    for (int l = 0; l < 3; ++l) {
        pull_update_kernel<<<NN / 4, 256, 0, stream>>>(rp, recs, egoIn, egoOut, outp,
                                                       gcW, gcb, biW, bib, l);
        const _Float16* t = egoOut; egoOut = (_Float16*)egoIn; egoIn = t;
    }
}

// Round 7
// 776.454 us; speedup vs baseline: 1.1177x; 1.1177x over previous
//
#include <hip/hip_runtime.h>
#include <cstdint>

#define NU 100000
#define NI 100000
#define NN 200000
#define NE 3200000
#define TXT 768
#define DD 32
#define NRANGE 8
#define ROWS_PER_RANGE (NN / NRANGE)   // 25000
#define NBJ 313        // blocks per range for ranged kernels

typedef _Float16 f16x8 __attribute__((ext_vector_type(8)));
typedef _Float16 f16x4 __attribute__((ext_vector_type(4)));
typedef float    f32x4 __attribute__((ext_vector_type(4)));

__device__ __forceinline__ float lrelu(float x) { return x >= 0.f ? x : 0.01f * x; }

// ---------------------------------------------------------------------------
// Copy pretrained 16-dim embeddings into ego16[:,0:16] (f16) and out[:,0:16]
// ---------------------------------------------------------------------------
__global__ void copy_emb_kernel(const float* __restrict__ uemb,
                                const float* __restrict__ iemb,
                                _Float16* __restrict__ ego16,
                                float* __restrict__ outp)
{
    int idx = blockIdx.x * blockDim.x + threadIdx.x;
    if (idx >= NN * 4) return;
    int n = idx >> 2, q = idx & 3;
    float4 v;
    if (n < NU) v = ((const float4*)uemb)[(size_t)n * 4 + q];
    else        v = ((const float4*)iemb)[(size_t)(n - NU) * 4 + q];
    f16x4 h;
    h[0] = (_Float16)v.x; h[1] = (_Float16)v.y;
    h[2] = (_Float16)v.z; h[3] = (_Float16)v.w;
    *(f16x4*)(ego16 + (size_t)n * 32 + q * 4) = h;
    ((float4*)outp)[(size_t)n * 32 + q] = v;
}

// ---------------------------------------------------------------------------
// MFMA MLP (both user+item in one launch): created = relu(X@W1)@W2.
// Blocks 0..511 -> users, 512..1023 -> items. One wave per 16-row tile.
// ---------------------------------------------------------------------------
__global__ __launch_bounds__(512) void mlp_mfma_kernel(
    const float* __restrict__ Xu, const float* __restrict__ Xi,
    const float* __restrict__ ueW1, const float* __restrict__ ueW2,
    const float* __restrict__ ieW1, const float* __restrict__ ieW2,
    _Float16* __restrict__ ego16,
    float* __restrict__ outp)
{
    __shared__ _Float16 W1s[24576];      // 48 KB: [kb(24)][half(2)][lane(64)][j(8)]
    __shared__ _Float16 hbuf[8][640];    // per-wave 16 x 40 (h, row-major, padded)

    const int tid  = threadIdx.x;
    const int lane = tid & 63;
    const int wv   = tid >> 6;

    const bool isU = blockIdx.x < 512;
    const float* X  = isU ? Xu : Xi;
    const float* W1 = isU ? ueW1 : ieW1;
    const float* W2 = isU ? ueW2 : ieW2;
    const int node_base = isU ? 0 : NU;
    const int bj = isU ? blockIdx.x : blockIdx.x - 512;

    for (int i = tid; i < 24576; i += 512) {
        int j   = i & 7;
        int ln  = (i >> 3) & 63;
        int kbH = i >> 9;
        int kb  = kbH >> 1, H = kbH & 1;
        int k   = kb * 32 + (ln >> 4) * 8 + j;
        int c   = H * 16 + (ln & 15);
        W1s[i] = (_Float16)W1[k * 32 + c];
    }

    f16x8 bw2;
    #pragma unroll
    for (int j = 0; j < 8; ++j)
        bw2[j] = (_Float16)W2[((lane >> 4) * 8 + j) * 16 + (lane & 15)];

    __syncthreads();

    _Float16* hb = &hbuf[wv][0];
    const int gw = bj * 8 + wv;                         // 0..4095
    const int t0 = (int)(((long)gw * 6250) >> 12);      // balanced tile ranges
    const int t1 = (int)(((long)(gw + 1) * 6250) >> 12);

    for (int tile = t0; tile < t1; ++tile) {
        const float* xp = X + (size_t)(tile * 16 + (lane & 15)) * TXT + (lane >> 4) * 8;
        f32x4 c0 = {0.f, 0.f, 0.f, 0.f};
        f32x4 c1 = {0.f, 0.f, 0.f, 0.f};

        #pragma unroll 4
        for (int kb = 0; kb < 24; ++kb) {
            float4 xa = *(const float4*)(xp + kb * 32);
            float4 xb = *(const float4*)(xp + kb * 32 + 4);
            f16x8 a;
            a[0] = (_Float16)xa.x; a[1] = (_Float16)xa.y;
            a[2] = (_Float16)xa.z; a[3] = (_Float16)xa.w;
            a[4] = (_Float16)xb.x; a[5] = (_Float16)xb.y;
            a[6] = (_Float16)xb.z; a[7] = (_Float16)xb.w;
            f16x8 b0 = *(const f16x8*)&W1s[(kb * 2 + 0) * 512 + lane * 8];
            f16x8 b1 = *(const f16x8*)&W1s[(kb * 2 + 1) * 512 + lane * 8];
            c0 = __builtin_amdgcn_mfma_f32_16x16x32_f16(a, b0, c0, 0, 0, 0);
            c1 = __builtin_amdgcn_mfma_f32_16x16x32_f16(a, b1, c1, 0, 0, 0);
        }

        #pragma unroll
        for (int j = 0; j < 4; ++j) {
            int r = (lane >> 4) * 4 + j;
            hb[r * 40 + (lane & 15)]      = (_Float16)fmaxf(c0[j], 0.f);
            hb[r * 40 + (lane & 15) + 16] = (_Float16)fmaxf(c1[j], 0.f);
        }
        const _Float16* ap = &hb[(lane & 15) * 40 + (lane >> 4) * 8];
        f16x4 lo = *(const f16x4*)ap;
        f16x4 hi = *(const f16x4*)(ap + 4);
        f16x8 a2;
        a2[0] = lo[0]; a2[1] = lo[1]; a2[2] = lo[2]; a2[3] = lo[3];
        a2[4] = hi[0]; a2[5] = hi[1]; a2[6] = hi[2]; a2[7] = hi[3];

        f32x4 c2 = {0.f, 0.f, 0.f, 0.f};
        c2 = __builtin_amdgcn_mfma_f32_16x16x32_f16(a2, bw2, c2, 0, 0, 0);

        const int rbase = node_base + tile * 16 + (lane >> 4) * 4;
        const int j2 = lane & 15;
        #pragma unroll
        for (int j = 0; j < 4; ++j) {
            float v = c2[j];
            ego16[(size_t)(rbase + j) * 32  + 16 + j2] = (_Float16)v;
            outp [(size_t)(rbase + j) * 128 + 16 + j2] = v;
        }
    }
}

// ---------------------------------------------------------------------------
// XCD-range-partitioned CSR build (block b&7 owns a row range -> L2-local)
// ---------------------------------------------------------------------------
__global__ __launch_bounds__(256) void count_ranged_kernel(const int* __restrict__ erow,
                                                           int* __restrict__ cnt)
{
    const int rlo = (blockIdx.x & 7) * ROWS_PER_RANGE;
    const int rhi = rlo + ROWS_PER_RANGE;
    const int bj  = blockIdx.x >> 3;
    const int4* e4 = (const int4*)erow;
    for (int c = bj * 256 + threadIdx.x; c < NE / 4; c += NBJ * 256) {
        int4 v = e4[c];
        if (v.x >= rlo && v.x < rhi) atomicAdd(&cnt[v.x], 1);
        if (v.y >= rlo && v.y < rhi) atomicAdd(&cnt[v.y], 1);
        if (v.z >= rlo && v.z < rhi) atomicAdd(&cnt[v.z], 1);
        if (v.w >= rlo && v.w < rhi) atomicAdd(&cnt[v.w], 1);
    }
}

__global__ __launch_bounds__(256) void scan_blk_kernel(const int* __restrict__ cnt,
                                                       int* __restrict__ rp,
                                                       int* __restrict__ bsum)
{
    __shared__ int ts[256];
    const int tid = threadIdx.x;
    const int base = blockIdx.x * 1024 + tid * 4;
    int v0 = (base + 0 < NN) ? cnt[base + 0] : 0;
    int v1 = (base + 1 < NN) ? cnt[base + 1] : 0;
    int v2 = (base + 2 < NN) ? cnt[base + 2] : 0;
    int v3 = (base + 3 < NN) ? cnt[base + 3] : 0;
    int s = v0 + v1 + v2 + v3;
    ts[tid] = s;
    __syncthreads();
    for (int off = 1; off < 256; off <<= 1) {
        int t = (tid >= off) ? ts[tid - off] : 0;
        __syncthreads();
        ts[tid] += t;
        __syncthreads();
    }
    int excl = ts[tid] - s;
    if (base + 0 < NN) rp[base + 0] = excl;
    if (base + 1 < NN) rp[base + 1] = excl + v0;
    if (base + 2 < NN) rp[base + 2] = excl + v0 + v1;
    if (base + 3 < NN) rp[base + 3] = excl + v0 + v1 + v2;
    if (tid == 255) bsum[blockIdx.x] = ts[255];
}

__global__ __launch_bounds__(256) void scan_bsum_kernel(int* __restrict__ bsum, int nblk)
{
    __shared__ int ts[256];
    const int tid = threadIdx.x;
    int v = (tid < nblk) ? bsum[tid] : 0;
    ts[tid] = v;
    __syncthreads();
    for (int off = 1; off < 256; off <<= 1) {
        int t = (tid >= off) ? ts[tid - off] : 0;
        __syncthreads();
        ts[tid] += t;
        __syncthreads();
    }
    if (tid < nblk) bsum[tid] = ts[tid] - v;
}

__global__ __launch_bounds__(256) void add_off_kernel(int* __restrict__ rp,
                                                      const int* __restrict__ bsum,
                                                      int* __restrict__ cur)
{
    int i = blockIdx.x * 256 + threadIdx.x;
    if (i < NN) {
        int v = rp[i] + bsum[i >> 10];
        rp[i] = v;
        cur[i] = v;
    }
    if (i == 0) rp[NN] = NE;
}

// rec.x = col | ((row & 63) << 18)  (col < 2^18; local row for 64-row blocks)
__global__ __launch_bounds__(256) void fill_ranged_kernel(const int* __restrict__ erow,
                                                          const int* __restrict__ ecol,
                                                          const float* __restrict__ eval,
                                                          int* __restrict__ cur,
                                                          uint2* __restrict__ recs)
{
    const int rlo = (blockIdx.x & 7) * ROWS_PER_RANGE;
    const int rhi = rlo + ROWS_PER_RANGE;
    const int bj  = blockIdx.x >> 3;
    const int4* e4 = (const int4*)erow;
    for (int c = bj * 256 + threadIdx.x; c < NE / 4; c += NBJ * 256) {
        int4 v = e4[c];
        int base = c * 4;
        if (v.x >= rlo && v.x < rhi) {
            int pos = atomicAdd(&cur[v.x], 1);
            recs[pos] = make_uint2((unsigned)ecol[base+0] | ((unsigned)(v.x & 63) << 18),
                                   __float_as_uint(eval[base+0]));
        }
        if (v.y >= rlo && v.y < rhi) {
            int pos = atomicAdd(&cur[v.y], 1);
            recs[pos] = make_uint2((unsigned)ecol[base+1] | ((unsigned)(v.y & 63) << 18),
                                   __float_as_uint(eval[base+1]));
        }
        if (v.z >= rlo && v.z < rhi) {
            int pos = atomicAdd(&cur[v.z], 1);
            recs[pos] = make_uint2((unsigned)ecol[base+2] | ((unsigned)(v.z & 63) << 18),
                                   __float_as_uint(eval[base+2]));
        }
        if (v.w >= rlo && v.w < rhi) {
            int pos = atomicAdd(&cur[v.w], 1);
            recs[pos] = make_uint2((unsigned)ecol[base+3] | ((unsigned)(v.w & 63) << 18),
                                   __float_as_uint(eval[base+3]));
        }
    }
}

// ---------------------------------------------------------------------------
// Segmented pull + update. Block owns 64 rows; 32 edge-slots x 8 dim-lanes
// walk the CSR span in contiguous runs, register-accumulating per row and
// flushing to an LDS f32 accumulator on row change (LDS atomics, sparse).
// Then 4 threads/row apply the two 32x32 transforms + lrelu + norm in-block.
// ---------------------------------------------------------------------------
__global__ __launch_bounds__(256) void pull_update_v2(
    const int* __restrict__ rp, const uint2* __restrict__ recs,
    const _Float16* __restrict__ egoIn, _Float16* __restrict__ egoOut,
    float* __restrict__ outp,
    const float* __restrict__ gcW, const float* __restrict__ gcb,
    const float* __restrict__ biW, const float* __restrict__ bib, int l)
{
    __shared__ float acc[64][33];    // 8.4 KB accumulator (pad 33 vs banks)
    __shared__ float Wg[32][36];     // stride 36: 16B-aligned rows
    __shared__ float Wb[32][36];
    __shared__ float bgs[32], bbs[32];

    const int tid = threadIdx.x;
    for (int i = tid; i < 64 * 33; i += 256) ((float*)acc)[i] = 0.f;
    for (int i = tid; i < 1024; i += 256) {
        Wg[i >> 5][i & 31] = gcW[l * 1024 + i];
        Wb[i >> 5][i & 31] = biW[l * 1024 + i];
    }
    if (tid < 32) { bgs[tid] = gcb[l * 32 + tid]; bbs[tid] = bib[l * 32 + tid]; }

    const int r0 = blockIdx.x * 64;
    const int eBeg = rp[r0], eEnd = rp[r0 + 64];
    __syncthreads();

    // ---- gather phase ----
    const int cnt = eEnd - eBeg;
    const int s   = tid >> 3;       // slot 0..31
    const int q   = tid & 7;        // dim quad 0..7
    const int L   = (cnt + 31) >> 5;
    const int e0  = eBeg + s * L;
    const int e1  = min(e0 + L, eEnd);

    float4 a4 = make_float4(0.f, 0.f, 0.f, 0.f);
    int curRl = -1;
    for (int e = e0; e < e1; ++e) {
        uint2 rec = recs[e];
        int col = rec.x & 0x3FFFF;
        int rl  = rec.x >> 18;
        float a = __uint_as_float(rec.y);
        f16x4 v = *(const f16x4*)(egoIn + (size_t)col * 32 + q * 4);
        if (rl != curRl) {
            if (curRl >= 0) {
                atomicAdd(&acc[curRl][q * 4 + 0], a4.x);
                atomicAdd(&acc[curRl][q * 4 + 1], a4.y);
                atomicAdd(&acc[curRl][q * 4 + 2], a4.z);
                atomicAdd(&acc[curRl][q * 4 + 3], a4.w);
            }
            a4 = make_float4(0.f, 0.f, 0.f, 0.f);
            curRl = rl;
        }
        a4.x += a * (float)v[0];
        a4.y += a * (float)v[1];
        a4.z += a * (float)v[2];
        a4.w += a * (float)v[3];
    }
    if (curRl >= 0) {
        atomicAdd(&acc[curRl][q * 4 + 0], a4.x);
        atomicAdd(&acc[curRl][q * 4 + 1], a4.y);
        atomicAdd(&acc[curRl][q * 4 + 2], a4.z);
        atomicAdd(&acc[curRl][q * 4 + 3], a4.w);
    }
    __syncthreads();

    // ---- update phase: 4 threads per row, 8 output dims each ----
    const int r    = tid >> 2;
    const int c    = tid & 3;
    const int node = r0 + r;
    const int j0   = c * 8;

    const _Float16* er = egoIn + (size_t)node * 32;
    f16x8 ev0 = *(const f16x8*)er;
    f16x8 ev1 = *(const f16x8*)(er + 8);
    f16x8 ev2 = *(const f16x8*)(er + 16);
    f16x8 ev3 = *(const f16x8*)(er + 24);

    float A[8], B[8];
    #pragma unroll
    for (int jj = 0; jj < 8; ++jj) { A[jj] = bgs[j0 + jj]; B[jj] = bbs[j0 + jj]; }

    #pragma unroll
    for (int kq = 0; kq < 4; ++kq) {
        #pragma unroll
        for (int kk = 0; kk < 8; ++kk) {
            const int k = kq * 8 + kk;
            float sk = acc[r][k];
            float evk = (kq == 0) ? (float)ev0[kk] : (kq == 1) ? (float)ev1[kk]
                      : (kq == 2) ? (float)ev2[kk] : (float)ev3[kk];
            float ek = sk * evk;
            f32x4 g0 = *(const f32x4*)&Wg[k][j0];
            f32x4 g1 = *(const f32x4*)&Wg[k][j0 + 4];
            f32x4 b0 = *(const f32x4*)&Wb[k][j0];
            f32x4 b1 = *(const f32x4*)&Wb[k][j0 + 4];
            A[0] += sk * g0[0]; A[1] += sk * g0[1]; A[2] += sk * g0[2]; A[3] += sk * g0[3];
            A[4] += sk * g1[0]; A[5] += sk * g1[1]; A[6] += sk * g1[2]; A[7] += sk * g1[3];
            B[0] += ek * b0[0]; B[1] += ek * b0[1]; B[2] += ek * b0[2]; B[3] += ek * b0[3];
            B[4] += ek * b1[0]; B[5] += ek * b1[1]; B[6] += ek * b1[2]; B[7] += ek * b1[3];
        }
    }

    float v[8];
    float ss = 0.f;
    #pragma unroll
    for (int jj = 0; jj < 8; ++jj) {
        float x = lrelu(A[jj]) + lrelu(B[jj]);
        v[jj] = x;
        ss += x * x;
    }
    ss += __shfl_xor(ss, 1, 64);
    ss += __shfl_xor(ss, 2, 64);
    float inv = 1.0f / fmaxf(sqrtf(ss), 1e-12f);

    f16x8 h;
    #pragma unroll
    for (int jj = 0; jj < 8; ++jj) h[jj] = (_Float16)v[jj];
    *(f16x8*)(egoOut + (size_t)node * 32 + j0) = h;

    float* op = outp + (size_t)node * 128 + (size_t)(l + 1) * 32 + j0;
    float4 o0 = make_float4(v[0] * inv, v[1] * inv, v[2] * inv, v[3] * inv);
    float4 o1 = make_float4(v[4] * inv, v[5] * inv, v[6] * inv, v[7] * inv);
    *(float4*)op       = o0;
    *(float4*)(op + 4) = o1;
}

// ---------------------------------------------------------------------------
extern "C" void kernel_launch(void* const* d_in, const int* in_sizes, int n_in,
                              void* d_out, int out_size, void* d_ws, size_t ws_size,
                              hipStream_t stream)
{
    const int*   erow = (const int*)d_in[0];
    const int*   ecol = (const int*)d_in[1];
    const float* evalp = (const float*)d_in[2];
    const float* une  = (const float*)d_in[3];
    const float* se   = (const float*)d_in[4];
    const float* uemb = (const float*)d_in[5];
    const float* iemb = (const float*)d_in[6];
    const float* ueW1 = (const float*)d_in[7];
    const float* ueW2 = (const float*)d_in[8];
    const float* ieW1 = (const float*)d_in[9];
    const float* ieW2 = (const float*)d_in[10];
    const float* gcW  = (const float*)d_in[11];
    const float* gcb  = (const float*)d_in[12];
    const float* biW  = (const float*)d_in[13];
    const float* bib  = (const float*)d_in[14];
    float* outp = (float*)d_out;

    _Float16* egoA16 = (_Float16*)d_ws;                 // NN*32 f16 = 12.8 MB
    _Float16* egoB16 = egoA16 + (size_t)NN * 32;        // 12.8 MB
    uint2* recs = (uint2*)(egoB16 + (size_t)NN * 32);   // NE uint2 = 25.6 MB
    int*   cnt  = (int*)(recs + (size_t)NE);            // NN
    int*   rp   = cnt + NN;                             // NN+1
    int*   cur  = rp + NN + 1;                          // NN
    int*   bsum = cur + NN;                             // 256

    const size_t need = (size_t)((char*)(bsum + 256) - (char*)d_ws);
    if (ws_size < need) return;   // ws is ~GB in this harness; guard only

    copy_emb_kernel<<<(NN * 4 + 255) / 256, 256, 0, stream>>>(uemb, iemb, egoA16, outp);
    mlp_mfma_kernel<<<1024, 512, 0, stream>>>(une, se, ueW1, ueW2, ieW1, ieW2,
                                              egoA16, outp);

    const int NBLK = (NN + 1023) / 1024;  // 196
    hipMemsetAsync(cnt, 0, (size_t)NN * sizeof(int), stream);
    count_ranged_kernel<<<NRANGE * NBJ, 256, 0, stream>>>(erow, cnt);
    scan_blk_kernel<<<NBLK, 256, 0, stream>>>(cnt, rp, bsum);
    scan_bsum_kernel<<<1, 256, 0, stream>>>(bsum, NBLK);
    add_off_kernel<<<(NN + 255) / 256, 256, 0, stream>>>(rp, bsum, cur);
    fill_ranged_kernel<<<NRANGE * NBJ, 256, 0, stream>>>(erow, ecol, evalp, cur, recs);

    const _Float16* egoIn = egoA16;
    _Float16* egoOut = egoB16;
    for (int l = 0; l < 3; ++l) {
        pull_update_v2<<<NN / 64, 256, 0, stream>>>(rp, recs, egoIn, egoOut, outp,
                                                    gcW, gcb, biW, bib, l);
        const _Float16* t = egoOut; egoOut = (_Float16*)egoIn; egoIn = t;
    }
}